// Round 1
// baseline (938.906 us; speedup 1.0000x reference)
//
#include <hip/hip_runtime.h>
#include <hip/hip_bf16.h>
#include <cstdint>
#include <cstddef>

#define BB 4
#define SS 2048
#define DM 1024
#define INNER 2048

typedef __attribute__((ext_vector_type(8))) __bf16 bf16x8;
typedef __attribute__((ext_vector_type(4))) float f32x4;
typedef __attribute__((ext_vector_type(8))) unsigned short ushort8;
typedef __attribute__((ext_vector_type(4))) unsigned short ushort4v;

#define GPTR(p) ((const __attribute__((address_space(1))) void*)(p))
#define LPTR(p) ((__attribute__((address_space(3))) void*)(p))

__device__ inline float b2f(unsigned short h) {
  union { unsigned u; float f; } v; v.u = ((unsigned)h) << 16; return v.f;
}
__device__ inline unsigned short f2b(float f) {
  unsigned u = __float_as_uint(f);
  u += 0x7fff + ((u >> 16) & 1);   // round-to-nearest-even
  return (unsigned short)(u >> 16);
}
__device__ inline float sigmoidf_(float x) { return 1.0f / (1.0f + __expf(-x)); }

// ---------------------------------------------------------------------------
// Transpose + cast: src fp32 [R][C] -> dst bf16 [C][R]
// ---------------------------------------------------------------------------
__global__ void transpose_cast_kernel(const float* __restrict__ src,
                                      unsigned short* __restrict__ dst,
                                      int R, int C) {
  __shared__ float tile[32][33];
  const int c0 = blockIdx.x * 32, r0 = blockIdx.y * 32;
  const int tx = threadIdx.x, ty = threadIdx.y;  // (32,8)
  #pragma unroll
  for (int j = ty; j < 32; j += 8)
    tile[j][tx] = src[(size_t)(r0 + j) * C + c0 + tx];
  __syncthreads();
  #pragma unroll
  for (int j = ty; j < 32; j += 8)
    dst[(size_t)(c0 + j) * R + r0 + tx] = f2b(tile[tx][j]);
}

// ---------------------------------------------------------------------------
// LayerNorm: x fp32 [8192][1024] -> xn bf16
// ---------------------------------------------------------------------------
__global__ __launch_bounds__(256) void layernorm_kernel(
    const float* __restrict__ x, const float* __restrict__ gamma,
    const float* __restrict__ beta, unsigned short* __restrict__ out) {
  const int row = blockIdx.x;
  const int tid = threadIdx.x;
  const float4 v = *(const float4*)(x + (size_t)row * DM + tid * 4);
  float s = v.x + v.y + v.z + v.w;
  #pragma unroll
  for (int o = 32; o >= 1; o >>= 1) s += __shfl_down(s, o, 64);
  __shared__ float red[8];
  const int wid = tid >> 6, lane = tid & 63;
  if (lane == 0) red[wid] = s;
  __syncthreads();
  const float mu = (red[0] + red[1] + red[2] + red[3]) * (1.f / DM);
  const float d0 = v.x - mu, d1 = v.y - mu, d2 = v.z - mu, d3 = v.w - mu;
  float sq = d0 * d0 + d1 * d1 + d2 * d2 + d3 * d3;
  #pragma unroll
  for (int o = 32; o >= 1; o >>= 1) sq += __shfl_down(sq, o, 64);
  if (lane == 0) red[4 + wid] = sq;
  __syncthreads();
  const float var = (red[4] + red[5] + red[6] + red[7]) * (1.f / DM);
  const float rs = rsqrtf(var + 1e-5f);
  const int c0 = tid * 4;
  ushort4v o4;
  o4[0] = f2b(d0 * rs * gamma[c0 + 0] + beta[c0 + 0]);
  o4[1] = f2b(d1 * rs * gamma[c0 + 1] + beta[c0 + 1]);
  o4[2] = f2b(d2 * rs * gamma[c0 + 2] + beta[c0 + 2]);
  o4[3] = f2b(d3 * rs * gamma[c0 + 3] + beta[c0 + 3]);
  *(ushort4v*)(out + (size_t)row * DM + c0) = o4;
}

// ---------------------------------------------------------------------------
// GEMM: C[M][N] = act(A[M][K] @ Bt[N][K]^T + bias)   (A,Bt bf16; acc fp32)
// OUTMODE 0: store bf16.  OUTMODE 1: store fp32 with residual add.
// 128x128 tile, BK=32, 256 threads = 4 waves (2x2 of 64x64 sub-tiles).
// ---------------------------------------------------------------------------
template <int ACT, int OUTMODE>
__global__ __launch_bounds__(256) void gemm_bt(
    const unsigned short* __restrict__ A, const unsigned short* __restrict__ Bt,
    const float* __restrict__ bias, void* __restrict__ Cout,
    const float* __restrict__ resid, int M, int N, int K) {
  __shared__ unsigned short Alds[128 * 32];
  __shared__ unsigned short Blds[128 * 32];
  const int tid = threadIdx.x;
  const int m0 = blockIdx.y * 128, n0 = blockIdx.x * 128;
  const int l = tid & 63, w = tid >> 6;
  const int wr = w >> 1, wc = w & 1;

  f32x4 acc[4][4];
  #pragma unroll
  for (int i = 0; i < 4; i++)
    #pragma unroll
    for (int j = 0; j < 4; j++) acc[i][j] = (f32x4){0.f, 0.f, 0.f, 0.f};

  // staging: tile = 512 chunks of 16B; thread handles chunks tid, tid+256
  const int c0 = tid, c1 = tid + 256;
  const unsigned short* Ag0 = A + (size_t)(m0 + (c0 >> 2)) * K + (c0 & 3) * 8;
  const unsigned short* Ag1 = A + (size_t)(m0 + (c1 >> 2)) * K + (c1 & 3) * 8;
  const unsigned short* Bg0 = Bt + (size_t)(n0 + (c0 >> 2)) * K + (c0 & 3) * 8;
  const unsigned short* Bg1 = Bt + (size_t)(n0 + (c1 >> 2)) * K + (c1 & 3) * 8;
  const int frag_off = (l & 15) * 32 + (l >> 4) * 8;  // elems within 64-row panel

  for (int k0 = 0; k0 < K; k0 += 32) {
    __builtin_amdgcn_global_load_lds(GPTR(Ag0 + k0), LPTR(&Alds[c0 * 8]), 16, 0, 0);
    __builtin_amdgcn_global_load_lds(GPTR(Ag1 + k0), LPTR(&Alds[c1 * 8]), 16, 0, 0);
    __builtin_amdgcn_global_load_lds(GPTR(Bg0 + k0), LPTR(&Blds[c0 * 8]), 16, 0, 0);
    __builtin_amdgcn_global_load_lds(GPTR(Bg1 + k0), LPTR(&Blds[c1 * 8]), 16, 0, 0);
    __syncthreads();
    bf16x8 af[4], bfv[4];
    #pragma unroll
    for (int m = 0; m < 4; m++)
      af[m] = *(const bf16x8*)(&Alds[(wr * 64 + m * 16) * 32 + frag_off]);
    #pragma unroll
    for (int n = 0; n < 4; n++)
      bfv[n] = *(const bf16x8*)(&Blds[(wc * 64 + n * 16) * 32 + frag_off]);
    #pragma unroll
    for (int m = 0; m < 4; m++)
      #pragma unroll
      for (int n = 0; n < 4; n++)
        acc[m][n] = __builtin_amdgcn_mfma_f32_16x16x32_bf16(af[m], bfv[n], acc[m][n], 0, 0, 0);
    __syncthreads();
  }

  // epilogue: C row = (l>>4)*4 + r, col = l&15 within each 16x16 fragment
  #pragma unroll
  for (int n = 0; n < 4; n++) {
    const int col = n0 + wc * 64 + n * 16 + (l & 15);
    const float bv = bias[col];
    #pragma unroll
    for (int m = 0; m < 4; m++) {
      const int rowb = m0 + wr * 64 + m * 16 + (l >> 4) * 4;
      #pragma unroll
      for (int r = 0; r < 4; r++) {
        float v = acc[m][n][r] + bv;
        if (ACT == 1) v = sigmoidf_(v);
        else if (ACT == 2) v = tanhf(v);
        const size_t idx = (size_t)(rowb + r) * N + col;
        if (OUTMODE == 0) ((unsigned short*)Cout)[idx] = f2b(v);
        else ((float*)Cout)[idx] = v + resid[idx];
      }
    }
  }
}

// ---------------------------------------------------------------------------
// Causal depthwise conv (K=3) + SiLU + gate.  proj bf16 [B*S][2*INNER].
// One block = one (b,t) row of 2048 channels; 8 channels/thread.
// ---------------------------------------------------------------------------
__global__ __launch_bounds__(256) void conv_gate_kernel(
    const unsigned short* __restrict__ proj, const float* __restrict__ conv_w,
    const float* __restrict__ conv_b, unsigned short* __restrict__ u) {
  const size_t idx = ((size_t)blockIdx.x * 256 + threadIdx.x) * 8;
  const int d = (int)(idx & (INNER - 1));
  const size_t bt = idx >> 11;
  const int t = (int)(bt & (SS - 1));
  const size_t rowbase = bt * (2 * INNER);
  const ushort8 zero = {0, 0, 0, 0, 0, 0, 0, 0};
  ushort8 p0 = *(const ushort8*)(proj + rowbase + d);
  ushort8 p1 = zero, p2 = zero;
  if (t >= 1) p1 = *(const ushort8*)(proj + rowbase - 2 * INNER + d);
  if (t >= 2) p2 = *(const ushort8*)(proj + rowbase - 4 * INNER + d);
  ushort8 g = *(const ushort8*)(proj + rowbase + INNER + d);
  ushort8 res;
  #pragma unroll
  for (int j = 0; j < 8; j++) {
    const int dj = d + j;
    // out[t] = w0*in[t-2] + w1*in[t-1] + w2*in[t]
    float sv = conv_b[dj] + conv_w[dj * 3] * b2f(p2[j]) +
               conv_w[dj * 3 + 1] * b2f(p1[j]) + conv_w[dj * 3 + 2] * b2f(p0[j]);
    float uu = sv * sigmoidf_(sv) * sigmoidf_(b2f(g[j]));
    res[j] = f2b(uu);
  }
  *(ushort8*)(u + idx) = res;
}

// ---------------------------------------------------------------------------
// Linear recurrence: state = a*state + b*u ; y = c*state + u (y over u in-place)
// One thread per (batch, channel).
// ---------------------------------------------------------------------------
__global__ __launch_bounds__(256) void scan_kernel(
    const unsigned short* __restrict__ a, const unsigned short* __restrict__ b,
    const unsigned short* __restrict__ c, unsigned short* __restrict__ u) {
  const int d = blockIdx.x * 256 + threadIdx.x;
  const size_t base = (size_t)blockIdx.y * SS * INNER + d;
  float state = 0.f;
  #pragma unroll 4
  for (int t = 0; t < SS; t++) {
    const size_t i = base + (size_t)t * INNER;
    const float at = b2f(a[i]), btv = b2f(b[i]), ct = b2f(c[i]), ut = b2f(u[i]);
    state = fmaf(at, state, btv * ut);
    u[i] = f2b(fmaf(ct, state, ut));
  }
}

// ---------------------------------------------------------------------------
extern "C" void kernel_launch(void* const* d_in, const int* in_sizes, int n_in,
                              void* d_out, int out_size, void* d_ws, size_t ws_size,
                              hipStream_t stream) {
  const float* x      = (const float*)d_in[0];
  const float* W_in   = (const float*)d_in[1];
  const float* b_in   = (const float*)d_in[2];
  const float* conv_w = (const float*)d_in[3];
  const float* conv_b = (const float*)d_in[4];
  const float* Wa     = (const float*)d_in[5];
  const float* ba     = (const float*)d_in[6];
  const float* Wb     = (const float*)d_in[7];
  const float* bb     = (const float*)d_in[8];
  const float* Wc     = (const float*)d_in[9];
  const float* bc     = (const float*)d_in[10];
  const float* Wo     = (const float*)d_in[11];
  const float* bo     = (const float*)d_in[12];
  const float* gamma  = (const float*)d_in[13];
  const float* beta   = (const float*)d_in[14];
  float* out = (float*)d_out;

  const size_t M = (size_t)BB * SS;  // 8192
  char* ws = (char*)d_ws;
  size_t off = 0;
  auto alloc = [&](size_t bytes) {
    char* p = ws + off;
    off += (bytes + 255) & ~(size_t)255;
    return p;
  };
  unsigned short* xnB  = (unsigned short*)alloc(M * DM * 2);            // 16 MB
  unsigned short* WinT = (unsigned short*)alloc((size_t)4096 * 1024 * 2);
  unsigned short* WaT  = (unsigned short*)alloc((size_t)2048 * 2048 * 2);
  unsigned short* WbT  = (unsigned short*)alloc((size_t)2048 * 2048 * 2);
  unsigned short* WcT  = (unsigned short*)alloc((size_t)2048 * 2048 * 2);
  unsigned short* WoT  = (unsigned short*)alloc((size_t)1024 * 2048 * 2);
  unsigned short* proj = (unsigned short*)alloc(M * 2 * INNER * 2);     // 64 MB
  unsigned short* uB   = (unsigned short*)alloc(M * INNER * 2);         // 32 MB
  unsigned short* cB   = (unsigned short*)alloc(M * INNER * 2);         // 32 MB
  unsigned short* aB = proj;                        // alias: proj dead after conv
  unsigned short* bB = proj + M * INNER;

  const dim3 tb(32, 8);
  transpose_cast_kernel<<<dim3(4096 / 32, 1024 / 32), tb, 0, stream>>>(W_in, WinT, 1024, 4096);
  transpose_cast_kernel<<<dim3(64, 64), tb, 0, stream>>>(Wa, WaT, 2048, 2048);
  transpose_cast_kernel<<<dim3(64, 64), tb, 0, stream>>>(Wb, WbT, 2048, 2048);
  transpose_cast_kernel<<<dim3(64, 64), tb, 0, stream>>>(Wc, WcT, 2048, 2048);
  transpose_cast_kernel<<<dim3(1024 / 32, 2048 / 32), tb, 0, stream>>>(Wo, WoT, 2048, 1024);

  layernorm_kernel<<<M, 256, 0, stream>>>(x, gamma, beta, xnB);

  // proj = xn @ W_in + b_in            [8192 x 4096]
  gemm_bt<0, 0><<<dim3(4096 / 128, M / 128), 256, 0, stream>>>(
      xnB, WinT, b_in, proj, nullptr, M, 4096, 1024);

  // u = silu(conv(projected)) * sigmoid(gate)
  conv_gate_kernel<<<(M * INNER) / (256 * 8), 256, 0, stream>>>(proj, conv_w, conv_b, uB);

  // a,b,c gates                        [8192 x 2048] each
  gemm_bt<1, 0><<<dim3(2048 / 128, M / 128), 256, 0, stream>>>(
      uB, WaT, ba, aB, nullptr, M, 2048, 2048);
  gemm_bt<1, 0><<<dim3(2048 / 128, M / 128), 256, 0, stream>>>(
      uB, WbT, bb, bB, nullptr, M, 2048, 2048);
  gemm_bt<2, 0><<<dim3(2048 / 128, M / 128), 256, 0, stream>>>(
      uB, WcT, bc, cB, nullptr, M, 2048, 2048);

  // recurrence (y overwrites u)
  scan_kernel<<<dim3(INNER / 256, BB), 256, 0, stream>>>(aB, bB, cB, uB);

  // out = x + y @ Wo + bo              [8192 x 1024] fp32
  gemm_bt<0, 1><<<dim3(1024 / 128, M / 128), 256, 0, stream>>>(
      uB, WoT, bo, out, x, M, 1024, 2048);
}

// Round 2
// 589.643 us; speedup vs baseline: 1.5923x; 1.5923x over previous
//
#include <hip/hip_runtime.h>
#include <hip/hip_bf16.h>
#include <cstdint>
#include <cstddef>

#define BB 4
#define SS 2048
#define DM 1024
#define INNER 2048
#define CHUNK 64
#define NCHK (SS / CHUNK)  // 32

typedef __attribute__((ext_vector_type(8))) __bf16 bf16x8;
typedef __attribute__((ext_vector_type(4))) float f32x4;
typedef __attribute__((ext_vector_type(8))) unsigned short ushort8;
typedef __attribute__((ext_vector_type(4))) unsigned short ushort4v;

#define GPTR(p) ((const __attribute__((address_space(1))) void*)(p))
#define LPTR(p) ((__attribute__((address_space(3))) void*)(p))

__device__ inline float b2f(unsigned short h) {
  union { unsigned u; float f; } v; v.u = ((unsigned)h) << 16; return v.f;
}
__device__ inline unsigned short f2b(float f) {
  unsigned u = __float_as_uint(f);
  u += 0x7fff + ((u >> 16) & 1);   // round-to-nearest-even
  return (unsigned short)(u >> 16);
}
__device__ inline float sigmoidf_(float x) { return 1.0f / (1.0f + __expf(-x)); }

// ---------------------------------------------------------------------------
// Transpose + cast: src fp32 [R][C] -> dst bf16 [C][R]
// ---------------------------------------------------------------------------
__global__ void transpose_cast_kernel(const float* __restrict__ src,
                                      unsigned short* __restrict__ dst,
                                      int R, int C) {
  __shared__ float tile[32][33];
  const int c0 = blockIdx.x * 32, r0 = blockIdx.y * 32;
  const int tx = threadIdx.x, ty = threadIdx.y;  // (32,8)
  #pragma unroll
  for (int j = ty; j < 32; j += 8)
    tile[j][tx] = src[(size_t)(r0 + j) * C + c0 + tx];
  __syncthreads();
  #pragma unroll
  for (int j = ty; j < 32; j += 8)
    dst[(size_t)(c0 + j) * R + r0 + tx] = f2b(tile[tx][j]);
}

// ---------------------------------------------------------------------------
// LayerNorm: x fp32 [8192][1024] -> xn bf16
// ---------------------------------------------------------------------------
__global__ __launch_bounds__(256) void layernorm_kernel(
    const float* __restrict__ x, const float* __restrict__ gamma,
    const float* __restrict__ beta, unsigned short* __restrict__ out) {
  const int row = blockIdx.x;
  const int tid = threadIdx.x;
  const float4 v = *(const float4*)(x + (size_t)row * DM + tid * 4);
  float s = v.x + v.y + v.z + v.w;
  #pragma unroll
  for (int o = 32; o >= 1; o >>= 1) s += __shfl_down(s, o, 64);
  __shared__ float red[8];
  const int wid = tid >> 6, lane = tid & 63;
  if (lane == 0) red[wid] = s;
  __syncthreads();
  const float mu = (red[0] + red[1] + red[2] + red[3]) * (1.f / DM);
  const float d0 = v.x - mu, d1 = v.y - mu, d2 = v.z - mu, d3 = v.w - mu;
  float sq = d0 * d0 + d1 * d1 + d2 * d2 + d3 * d3;
  #pragma unroll
  for (int o = 32; o >= 1; o >>= 1) sq += __shfl_down(sq, o, 64);
  if (lane == 0) red[4 + wid] = sq;
  __syncthreads();
  const float var = (red[4] + red[5] + red[6] + red[7]) * (1.f / DM);
  const float rs = rsqrtf(var + 1e-5f);
  const int c0 = tid * 4;
  ushort4v o4;
  o4[0] = f2b(d0 * rs * gamma[c0 + 0] + beta[c0 + 0]);
  o4[1] = f2b(d1 * rs * gamma[c0 + 1] + beta[c0 + 1]);
  o4[2] = f2b(d2 * rs * gamma[c0 + 2] + beta[c0 + 2]);
  o4[3] = f2b(d3 * rs * gamma[c0 + 3] + beta[c0 + 3]);
  *(ushort4v*)(out + (size_t)row * DM + c0) = o4;
}

// ---------------------------------------------------------------------------
// GEMM: C[M][N] = act(A[M][K] @ Bt[N][K]^T + bias)   (A,Bt bf16; acc fp32)
// OUTMODE 0: store bf16.  OUTMODE 1: fp32 + residual.  OUTMODE 2: abc-fused
// (cols [0,2048) sigmoid->seg0, [2048,4096) sigmoid->seg1, [4096,6144) tanh->seg2;
//  segments contiguous [M][2048] blocks starting at Cout).
// ---------------------------------------------------------------------------
template <int ACT, int OUTMODE>
__global__ __launch_bounds__(256) void gemm_bt(
    const unsigned short* __restrict__ A, const unsigned short* __restrict__ Bt,
    const float* __restrict__ bias, void* __restrict__ Cout,
    const float* __restrict__ resid, int M, int N, int K) {
  __shared__ unsigned short Alds[128 * 32];
  __shared__ unsigned short Blds[128 * 32];
  const int tid = threadIdx.x;
  const int m0 = blockIdx.y * 128, n0 = blockIdx.x * 128;
  const int l = tid & 63, w = tid >> 6;
  const int wr = w >> 1, wc = w & 1;

  f32x4 acc[4][4];
  #pragma unroll
  for (int i = 0; i < 4; i++)
    #pragma unroll
    for (int j = 0; j < 4; j++) acc[i][j] = (f32x4){0.f, 0.f, 0.f, 0.f};

  const int c0 = tid, c1 = tid + 256;
  const unsigned short* Ag0 = A + (size_t)(m0 + (c0 >> 2)) * K + (c0 & 3) * 8;
  const unsigned short* Ag1 = A + (size_t)(m0 + (c1 >> 2)) * K + (c1 & 3) * 8;
  const unsigned short* Bg0 = Bt + (size_t)(n0 + (c0 >> 2)) * K + (c0 & 3) * 8;
  const unsigned short* Bg1 = Bt + (size_t)(n0 + (c1 >> 2)) * K + (c1 & 3) * 8;
  const int frag_off = (l & 15) * 32 + (l >> 4) * 8;

  for (int k0 = 0; k0 < K; k0 += 32) {
    __builtin_amdgcn_global_load_lds(GPTR(Ag0 + k0), LPTR(&Alds[c0 * 8]), 16, 0, 0);
    __builtin_amdgcn_global_load_lds(GPTR(Ag1 + k0), LPTR(&Alds[c1 * 8]), 16, 0, 0);
    __builtin_amdgcn_global_load_lds(GPTR(Bg0 + k0), LPTR(&Blds[c0 * 8]), 16, 0, 0);
    __builtin_amdgcn_global_load_lds(GPTR(Bg1 + k0), LPTR(&Blds[c1 * 8]), 16, 0, 0);
    __syncthreads();
    bf16x8 af[4], bfv[4];
    #pragma unroll
    for (int m = 0; m < 4; m++)
      af[m] = *(const bf16x8*)(&Alds[(wr * 64 + m * 16) * 32 + frag_off]);
    #pragma unroll
    for (int n = 0; n < 4; n++)
      bfv[n] = *(const bf16x8*)(&Blds[(wc * 64 + n * 16) * 32 + frag_off]);
    #pragma unroll
    for (int m = 0; m < 4; m++)
      #pragma unroll
      for (int n = 0; n < 4; n++)
        acc[m][n] = __builtin_amdgcn_mfma_f32_16x16x32_bf16(af[m], bfv[n], acc[m][n], 0, 0, 0);
    __syncthreads();
  }

  #pragma unroll
  for (int n = 0; n < 4; n++) {
    const int col = n0 + wc * 64 + n * 16 + (l & 15);
    const float bv = bias[col];
    #pragma unroll
    for (int m = 0; m < 4; m++) {
      const int rowb = m0 + wr * 64 + m * 16 + (l >> 4) * 4;
      #pragma unroll
      for (int r = 0; r < 4; r++) {
        float v = acc[m][n][r] + bv;
        if (OUTMODE == 2) {
          const int seg = col >> 11;
          v = (seg == 2) ? tanhf(v) : sigmoidf_(v);
          const size_t idx = (size_t)seg * M * 2048 + (size_t)(rowb + r) * 2048 + (col & 2047);
          ((unsigned short*)Cout)[idx] = f2b(v);
        } else {
          if (ACT == 1) v = sigmoidf_(v);
          else if (ACT == 2) v = tanhf(v);
          const size_t idx = (size_t)(rowb + r) * N + col;
          if (OUTMODE == 0) ((unsigned short*)Cout)[idx] = f2b(v);
          else ((float*)Cout)[idx] = v + resid[idx];
        }
      }
    }
  }
}

// ---------------------------------------------------------------------------
// Causal depthwise conv (K=3) + SiLU + gate.  proj bf16 [B*S][2*INNER].
// ---------------------------------------------------------------------------
__global__ __launch_bounds__(256) void conv_gate_kernel(
    const unsigned short* __restrict__ proj, const float* __restrict__ conv_w,
    const float* __restrict__ conv_b, unsigned short* __restrict__ u) {
  const size_t idx = ((size_t)blockIdx.x * 256 + threadIdx.x) * 8;
  const int d = (int)(idx & (INNER - 1));
  const size_t bt = idx >> 11;
  const int t = (int)(bt & (SS - 1));
  const size_t rowbase = bt * (2 * INNER);
  const ushort8 zero = {0, 0, 0, 0, 0, 0, 0, 0};
  ushort8 p0 = *(const ushort8*)(proj + rowbase + d);
  ushort8 p1 = zero, p2 = zero;
  if (t >= 1) p1 = *(const ushort8*)(proj + rowbase - 2 * INNER + d);
  if (t >= 2) p2 = *(const ushort8*)(proj + rowbase - 4 * INNER + d);
  ushort8 g = *(const ushort8*)(proj + rowbase + INNER + d);
  ushort8 res;
  #pragma unroll
  for (int j = 0; j < 8; j++) {
    const int dj = d + j;
    float sv = conv_b[dj] + conv_w[dj * 3] * b2f(p2[j]) +
               conv_w[dj * 3 + 1] * b2f(p1[j]) + conv_w[dj * 3 + 2] * b2f(p0[j]);
    float uu = sv * sigmoidf_(sv) * sigmoidf_(b2f(g[j]));
    res[j] = f2b(uu);
  }
  *(ushort8*)(u + idx) = res;
}

// ---------------------------------------------------------------------------
// Chunked parallel scan, 3 phases. state = a*state + b*u; y = c*state + u.
// Phase 1: per (batch, chunk, 4ch) -> P = prod(a), S = local scan (0-init).
// ---------------------------------------------------------------------------
__global__ __launch_bounds__(256) void scan_phase1(
    const unsigned short* __restrict__ a, const unsigned short* __restrict__ b,
    const unsigned short* __restrict__ u,
    float* __restrict__ P, float* __restrict__ S) {
  const int g = blockIdx.x * 256 + threadIdx.x;   // 65536 threads
  const int ch = (g & (INNER / 4 - 1)) * 4;
  const int chunk = (g >> 9) & (NCHK - 1);
  const int bb = g >> 14;
  size_t base = ((size_t)bb * SS + (size_t)chunk * CHUNK) * INNER + ch;
  float st0 = 0.f, st1 = 0.f, st2 = 0.f, st3 = 0.f;
  float p0 = 1.f, p1 = 1.f, p2 = 1.f, p3 = 1.f;
  for (int t = 0; t < CHUNK; t++) {
    const ushort4v av = *(const ushort4v*)(a + base);
    const ushort4v bv = *(const ushort4v*)(b + base);
    const ushort4v uv = *(const ushort4v*)(u + base);
    const float a0 = b2f(av[0]), a1 = b2f(av[1]), a2 = b2f(av[2]), a3 = b2f(av[3]);
    st0 = fmaf(a0, st0, b2f(bv[0]) * b2f(uv[0])); p0 *= a0;
    st1 = fmaf(a1, st1, b2f(bv[1]) * b2f(uv[1])); p1 *= a1;
    st2 = fmaf(a2, st2, b2f(bv[2]) * b2f(uv[2])); p2 *= a2;
    st3 = fmaf(a3, st3, b2f(bv[3]) * b2f(uv[3])); p3 *= a3;
    base += INNER;
  }
  const size_t o = ((size_t)bb * NCHK + chunk) * INNER + ch;
  *(float4*)(P + o) = (float4){p0, p1, p2, p3};
  *(float4*)(S + o) = (float4){st0, st1, st2, st3};
}

// Phase 2: per (batch, channel): sequential scan over 32 chunk summaries.
__global__ __launch_bounds__(256) void scan_phase2(
    const float* __restrict__ P, const float* __restrict__ S,
    float* __restrict__ Carry) {
  const int g = blockIdx.x * 256 + threadIdx.x;   // 8192 threads
  const int ch = g & (INNER - 1);
  const int bb = g >> 11;
  float carry = 0.f;
  for (int k = 0; k < NCHK; k++) {
    const size_t o = ((size_t)bb * NCHK + k) * INNER + ch;
    Carry[o] = carry;
    carry = fmaf(P[o], carry, S[o]);
  }
}

// Phase 3: redo local scan seeded with carry; y = c*state + u (in-place on u).
__global__ __launch_bounds__(256) void scan_phase3(
    const unsigned short* __restrict__ a, const unsigned short* __restrict__ b,
    const unsigned short* __restrict__ c, unsigned short* __restrict__ u,
    const float* __restrict__ Carry) {
  const int g = blockIdx.x * 256 + threadIdx.x;   // 65536 threads
  const int ch = (g & (INNER / 4 - 1)) * 4;
  const int chunk = (g >> 9) & (NCHK - 1);
  const int bb = g >> 14;
  size_t base = ((size_t)bb * SS + (size_t)chunk * CHUNK) * INNER + ch;
  const size_t o = ((size_t)bb * NCHK + chunk) * INNER + ch;
  const float4 cv = *(const float4*)(Carry + o);
  float st0 = cv.x, st1 = cv.y, st2 = cv.z, st3 = cv.w;
  for (int t = 0; t < CHUNK; t++) {
    const ushort4v av = *(const ushort4v*)(a + base);
    const ushort4v bv = *(const ushort4v*)(b + base);
    const ushort4v ccv = *(const ushort4v*)(c + base);
    const ushort4v uv = *(const ushort4v*)(u + base);
    const float u0 = b2f(uv[0]), u1 = b2f(uv[1]), u2 = b2f(uv[2]), u3 = b2f(uv[3]);
    st0 = fmaf(b2f(av[0]), st0, b2f(bv[0]) * u0);
    st1 = fmaf(b2f(av[1]), st1, b2f(bv[1]) * u1);
    st2 = fmaf(b2f(av[2]), st2, b2f(bv[2]) * u2);
    st3 = fmaf(b2f(av[3]), st3, b2f(bv[3]) * u3);
    ushort4v yv;
    yv[0] = f2b(fmaf(b2f(ccv[0]), st0, u0));
    yv[1] = f2b(fmaf(b2f(ccv[1]), st1, u1));
    yv[2] = f2b(fmaf(b2f(ccv[2]), st2, u2));
    yv[3] = f2b(fmaf(b2f(ccv[3]), st3, u3));
    *(ushort4v*)(u + base) = yv;
    base += INNER;
  }
}

// ---------------------------------------------------------------------------
extern "C" void kernel_launch(void* const* d_in, const int* in_sizes, int n_in,
                              void* d_out, int out_size, void* d_ws, size_t ws_size,
                              hipStream_t stream) {
  const float* x      = (const float*)d_in[0];
  const float* W_in   = (const float*)d_in[1];
  const float* b_in   = (const float*)d_in[2];
  const float* conv_w = (const float*)d_in[3];
  const float* conv_b = (const float*)d_in[4];
  const float* Wa     = (const float*)d_in[5];
  const float* ba     = (const float*)d_in[6];
  const float* Wb     = (const float*)d_in[7];
  const float* b_b    = (const float*)d_in[8];
  const float* Wc     = (const float*)d_in[9];
  const float* bc     = (const float*)d_in[10];
  const float* Wo     = (const float*)d_in[11];
  const float* bo     = (const float*)d_in[12];
  const float* gamma  = (const float*)d_in[13];
  const float* beta   = (const float*)d_in[14];
  float* out = (float*)d_out;

  const size_t M = (size_t)BB * SS;  // 8192
  char* ws = (char*)d_ws;
  size_t off = 0;
  auto alloc = [&](size_t bytes) {
    char* p = ws + off;
    off += (bytes + 255) & ~(size_t)255;
    return p;
  };
  unsigned short* WinT  = (unsigned short*)alloc((size_t)4096 * 1024 * 2);  // 8 MB
  unsigned short* WabcT = (unsigned short*)alloc((size_t)6144 * 2048 * 2);  // 24 MB
  unsigned short* WoT   = (unsigned short*)alloc((size_t)1024 * 2048 * 2);  // 4 MB
  float*          biasABC = (float*)alloc(6144 * 4);
  unsigned short* xnB   = (unsigned short*)alloc(M * DM * 2);               // 16 MB
  unsigned short* uB    = (unsigned short*)alloc(M * INNER * 2);            // 32 MB
  unsigned short* abc   = (unsigned short*)alloc(3 * M * INNER * 2);        // 96 MB
  unsigned short* proj = abc;                   // first GEMM output (64 MB < 96 MB)
  unsigned short* aB = abc;
  unsigned short* bB = abc + M * INNER;
  unsigned short* cB = abc + 2 * M * INNER;
  // xnB is dead after the proj GEMM; reuse it for scan phase buffers (3 MB < 16 MB)
  float* Pbuf  = (float*)xnB;
  float* Sbuf  = Pbuf + (size_t)BB * NCHK * INNER;
  float* Carry = Sbuf + (size_t)BB * NCHK * INNER;

  hipMemcpyAsync(biasABC,        ba,  2048 * 4, hipMemcpyDeviceToDevice, stream);
  hipMemcpyAsync(biasABC + 2048, b_b, 2048 * 4, hipMemcpyDeviceToDevice, stream);
  hipMemcpyAsync(biasABC + 4096, bc,  2048 * 4, hipMemcpyDeviceToDevice, stream);

  const dim3 tb(32, 8);
  transpose_cast_kernel<<<dim3(128, 32), tb, 0, stream>>>(W_in, WinT, 1024, 4096);
  transpose_cast_kernel<<<dim3(64, 64), tb, 0, stream>>>(Wa, WabcT, 2048, 2048);
  transpose_cast_kernel<<<dim3(64, 64), tb, 0, stream>>>(Wb, WabcT + 2048 * 2048, 2048, 2048);
  transpose_cast_kernel<<<dim3(64, 64), tb, 0, stream>>>(Wc, WabcT + 2 * 2048 * 2048, 2048, 2048);
  transpose_cast_kernel<<<dim3(32, 64), tb, 0, stream>>>(Wo, WoT, 2048, 1024);

  layernorm_kernel<<<M, 256, 0, stream>>>(x, gamma, beta, xnB);

  // proj = xn @ W_in + b_in            [8192 x 4096]
  gemm_bt<0, 0><<<dim3(32, 64), 256, 0, stream>>>(
      xnB, WinT, b_in, proj, nullptr, M, 4096, 1024);

  // u = silu(conv(projected)) * sigmoid(gate)
  conv_gate_kernel<<<(M * INNER) / (256 * 8), 256, 0, stream>>>(proj, conv_w, conv_b, uB);

  // a,b,c fused: [8192 x 6144] over concatenated [Wa;Wb;Wc]^T
  gemm_bt<0, 2><<<dim3(48, 64), 256, 0, stream>>>(
      uB, WabcT, biasABC, abc, nullptr, M, 6144, 2048);

  // chunked scan (y overwrites u)
  scan_phase1<<<256, 256, 0, stream>>>(aB, bB, uB, Pbuf, Sbuf);
  scan_phase2<<<32, 256, 0, stream>>>(Pbuf, Sbuf, Carry);
  scan_phase3<<<256, 256, 0, stream>>>(aB, bB, cB, uB, Carry);

  // out = x + y @ Wo + bo              [8192 x 1024] fp32
  gemm_bt<0, 1><<<dim3(8, 64), 256, 0, stream>>>(
      uB, WoT, bo, out, x, M, 1024, 2048);
}

// Round 3
// 521.029 us; speedup vs baseline: 1.8020x; 1.1317x over previous
//
#include <hip/hip_runtime.h>
#include <hip/hip_bf16.h>
#include <cstdint>
#include <cstddef>

#define BB 4
#define SS 2048
#define DM 1024
#define INNER 2048
#define CHUNK 64
#define NCHK (SS / CHUNK)  // 32

typedef __attribute__((ext_vector_type(8))) __bf16 bf16x8;
typedef __attribute__((ext_vector_type(4))) float f32x4;
typedef __attribute__((ext_vector_type(8))) unsigned short ushort8;
typedef __attribute__((ext_vector_type(4))) unsigned short ushort4v;

#define GPTR(p) ((const __attribute__((address_space(1))) void*)(p))
#define LPTR(p) ((__attribute__((address_space(3))) void*)(p))

__device__ inline float b2f(unsigned short h) {
  union { unsigned u; float f; } v; v.u = ((unsigned)h) << 16; return v.f;
}
__device__ inline unsigned short f2b(float f) {
  unsigned u = __float_as_uint(f);
  u += 0x7fff + ((u >> 16) & 1);   // round-to-nearest-even
  return (unsigned short)(u >> 16);
}
__device__ inline float sigmoidf_(float x) { return 1.0f / (1.0f + __expf(-x)); }

// ---------------------------------------------------------------------------
// Transpose + cast: src fp32 [R][C] -> dst bf16 [C][R]
// ---------------------------------------------------------------------------
__global__ void transpose_cast_kernel(const float* __restrict__ src,
                                      unsigned short* __restrict__ dst,
                                      int R, int C) {
  __shared__ float tile[32][33];
  const int c0 = blockIdx.x * 32, r0 = blockIdx.y * 32;
  const int tx = threadIdx.x, ty = threadIdx.y;  // (32,8)
  #pragma unroll
  for (int j = ty; j < 32; j += 8)
    tile[j][tx] = src[(size_t)(r0 + j) * C + c0 + tx];
  __syncthreads();
  #pragma unroll
  for (int j = ty; j < 32; j += 8)
    dst[(size_t)(c0 + j) * R + r0 + tx] = f2b(tile[tx][j]);
}

// ---------------------------------------------------------------------------
// LayerNorm: x fp32 [8192][1024] -> xn bf16
// ---------------------------------------------------------------------------
__global__ __launch_bounds__(256) void layernorm_kernel(
    const float* __restrict__ x, const float* __restrict__ gamma,
    const float* __restrict__ beta, unsigned short* __restrict__ out) {
  const int row = blockIdx.x;
  const int tid = threadIdx.x;
  const float4 v = *(const float4*)(x + (size_t)row * DM + tid * 4);
  float s = v.x + v.y + v.z + v.w;
  #pragma unroll
  for (int o = 32; o >= 1; o >>= 1) s += __shfl_down(s, o, 64);
  __shared__ float red[8];
  const int wid = tid >> 6, lane = tid & 63;
  if (lane == 0) red[wid] = s;
  __syncthreads();
  const float mu = (red[0] + red[1] + red[2] + red[3]) * (1.f / DM);
  const float d0 = v.x - mu, d1 = v.y - mu, d2 = v.z - mu, d3 = v.w - mu;
  float sq = d0 * d0 + d1 * d1 + d2 * d2 + d3 * d3;
  #pragma unroll
  for (int o = 32; o >= 1; o >>= 1) sq += __shfl_down(sq, o, 64);
  if (lane == 0) red[4 + wid] = sq;
  __syncthreads();
  const float var = (red[4] + red[5] + red[6] + red[7]) * (1.f / DM);
  const float rs = rsqrtf(var + 1e-5f);
  const int c0 = tid * 4;
  ushort4v o4;
  o4[0] = f2b(d0 * rs * gamma[c0 + 0] + beta[c0 + 0]);
  o4[1] = f2b(d1 * rs * gamma[c0 + 1] + beta[c0 + 1]);
  o4[2] = f2b(d2 * rs * gamma[c0 + 2] + beta[c0 + 2]);
  o4[3] = f2b(d3 * rs * gamma[c0 + 3] + beta[c0 + 3]);
  *(ushort4v*)(out + (size_t)row * DM + c0) = o4;
}

// ---------------------------------------------------------------------------
// Deep-pipelined 256x256 GEMM, BK=32, 512 threads (8 waves, 2Mx4N), 3-deep
// LDS ring (96 KB), counted vmcnt(4) (never drained to 0 in the loop),
// XOR-swizzled LDS (T2, via pre-swizzled global source), setprio around MFMA.
// C[M][N] = act(A[M][K] @ Bt[N][K]^T + bias)
// OUTMODE 0: bf16 store.  OUTMODE 2: abc-fused (seg 0/1 sigmoid, seg 2 tanh,
// segments written as contiguous [M][2048] blocks).
// ---------------------------------------------------------------------------
template <int OUTMODE>
__global__ __launch_bounds__(512, 2) void gemm256(
    const unsigned short* __restrict__ A, const unsigned short* __restrict__ Bt,
    const float* __restrict__ bias, void* __restrict__ Cout,
    int M, int N, int K) {
  __shared__ unsigned short lds[3 * 16384];  // 96 KB: 3 bufs x (A 8192 + B 8192)
  const int tid = threadIdx.x;
  const int m0 = blockIdx.y * 256, n0 = blockIdx.x * 256;
  const int l = tid & 63, w = tid >> 6;
  const int wr = w >> 2, wc = w & 3;          // 2 x 4 wave grid
  const int NT = K >> 5;                      // K-tiles of 32

  // swizzled fragment slot: global k-slot (l>>4) lives at LDS slot (l>>4)^swz
  const int slr = ((l >> 4) ^ (l & 3) ^ ((l >> 2) & 3)) & 3;
  const int afo = wr * 4096 + (l & 15) * 32 + slr * 8;           // + mf*512
  const int bfo = 8192 + wc * 2048 + (l & 15) * 32 + slr * 8;    // + nf*512

  f32x4 acc[8][4];
  #pragma unroll
  for (int i = 0; i < 8; i++)
    #pragma unroll
    for (int j = 0; j < 4; j++) acc[i][j] = (f32x4){0.f, 0.f, 0.f, 0.f};

  // stage full A (or B) K-tile of tile kt into buffer at elem-offset bufo.
  // dest linear: unit q = row*4 + slot (16B units); source k-slot pre-swizzled.
  auto stageA = [&](int kt, int bufo) {
    int ktw = kt; if (ktw >= NT) ktw -= NT;
    const int k0 = ktw << 5;
    #pragma unroll
    for (int i = 0; i < 2; i++) {
      const int q = i * 512 + tid;
      const int row = q >> 2;
      const int ss = (q ^ row ^ (row >> 2)) & 3;
      __builtin_amdgcn_global_load_lds(
          GPTR(A + (size_t)(m0 + row) * K + k0 + ss * 8),
          LPTR(&lds[bufo + q * 8]), 16, 0, 0);
    }
  };
  auto stageB = [&](int kt, int bufo) {
    int ktw = kt; if (ktw >= NT) ktw -= NT;
    const int k0 = ktw << 5;
    #pragma unroll
    for (int i = 0; i < 2; i++) {
      const int q = i * 512 + tid;
      const int row = q >> 2;
      const int ss = (q ^ row ^ (row >> 2)) & 3;
      __builtin_amdgcn_global_load_lds(
          GPTR(Bt + (size_t)(n0 + row) * K + k0 + ss * 8),
          LPTR(&lds[bufo + 8192 + q * 8]), 16, 0, 0);
    }
  };

  // prologue: tiles 0,1 in flight; wait tile 0 only (4 newest stay in flight)
  stageA(0, 0); stageB(0, 0);
  stageA(1, 16384); stageB(1, 16384);
  __builtin_amdgcn_sched_barrier(0);
  asm volatile("s_waitcnt vmcnt(4)" ::: "memory");
  __builtin_amdgcn_sched_barrier(0);
  __builtin_amdgcn_s_barrier();
  __builtin_amdgcn_sched_barrier(0);

  int tb = 0;
  for (int t = 0; t < NT; t++) {
    const int tbo = tb * 16384;
    int pfb = tb + 2; if (pfb >= 3) pfb -= 3;
    const int pfo = pfb * 16384;
    // ---- phase 1: m-frags 0-3 x all n-frags, stage A of tile t+2 ----
    bf16x8 a0 = *(const bf16x8*)&lds[tbo + afo + 0 * 512];
    bf16x8 a1 = *(const bf16x8*)&lds[tbo + afo + 1 * 512];
    bf16x8 a2 = *(const bf16x8*)&lds[tbo + afo + 2 * 512];
    bf16x8 a3 = *(const bf16x8*)&lds[tbo + afo + 3 * 512];
    bf16x8 b0 = *(const bf16x8*)&lds[tbo + bfo + 0 * 512];
    bf16x8 b1 = *(const bf16x8*)&lds[tbo + bfo + 1 * 512];
    bf16x8 b2 = *(const bf16x8*)&lds[tbo + bfo + 2 * 512];
    bf16x8 b3 = *(const bf16x8*)&lds[tbo + bfo + 3 * 512];
    stageA(t + 2, pfo);
    __builtin_amdgcn_sched_barrier(0);
    __builtin_amdgcn_s_barrier();
    __builtin_amdgcn_sched_barrier(0);
    __builtin_amdgcn_s_setprio(1);
    acc[0][0] = __builtin_amdgcn_mfma_f32_16x16x32_bf16(a0, b0, acc[0][0], 0, 0, 0);
    acc[0][1] = __builtin_amdgcn_mfma_f32_16x16x32_bf16(a0, b1, acc[0][1], 0, 0, 0);
    acc[0][2] = __builtin_amdgcn_mfma_f32_16x16x32_bf16(a0, b2, acc[0][2], 0, 0, 0);
    acc[0][3] = __builtin_amdgcn_mfma_f32_16x16x32_bf16(a0, b3, acc[0][3], 0, 0, 0);
    acc[1][0] = __builtin_amdgcn_mfma_f32_16x16x32_bf16(a1, b0, acc[1][0], 0, 0, 0);
    acc[1][1] = __builtin_amdgcn_mfma_f32_16x16x32_bf16(a1, b1, acc[1][1], 0, 0, 0);
    acc[1][2] = __builtin_amdgcn_mfma_f32_16x16x32_bf16(a1, b2, acc[1][2], 0, 0, 0);
    acc[1][3] = __builtin_amdgcn_mfma_f32_16x16x32_bf16(a1, b3, acc[1][3], 0, 0, 0);
    acc[2][0] = __builtin_amdgcn_mfma_f32_16x16x32_bf16(a2, b0, acc[2][0], 0, 0, 0);
    acc[2][1] = __builtin_amdgcn_mfma_f32_16x16x32_bf16(a2, b1, acc[2][1], 0, 0, 0);
    acc[2][2] = __builtin_amdgcn_mfma_f32_16x16x32_bf16(a2, b2, acc[2][2], 0, 0, 0);
    acc[2][3] = __builtin_amdgcn_mfma_f32_16x16x32_bf16(a2, b3, acc[2][3], 0, 0, 0);
    acc[3][0] = __builtin_amdgcn_mfma_f32_16x16x32_bf16(a3, b0, acc[3][0], 0, 0, 0);
    acc[3][1] = __builtin_amdgcn_mfma_f32_16x16x32_bf16(a3, b1, acc[3][1], 0, 0, 0);
    acc[3][2] = __builtin_amdgcn_mfma_f32_16x16x32_bf16(a3, b2, acc[3][2], 0, 0, 0);
    acc[3][3] = __builtin_amdgcn_mfma_f32_16x16x32_bf16(a3, b3, acc[3][3], 0, 0, 0);
    __builtin_amdgcn_s_setprio(0);
    __builtin_amdgcn_sched_barrier(0);
    __builtin_amdgcn_s_barrier();
    __builtin_amdgcn_sched_barrier(0);
    // ---- phase 2: m-frags 4-7 (B reused), stage B of tile t+2 ----
    bf16x8 a4 = *(const bf16x8*)&lds[tbo + afo + 4 * 512];
    bf16x8 a5 = *(const bf16x8*)&lds[tbo + afo + 5 * 512];
    bf16x8 a6 = *(const bf16x8*)&lds[tbo + afo + 6 * 512];
    bf16x8 a7 = *(const bf16x8*)&lds[tbo + afo + 7 * 512];
    stageB(t + 2, pfo);
    __builtin_amdgcn_sched_barrier(0);
    // tile t+1 fully resident after this (only tile t+2's 4 loads in flight)
    asm volatile("s_waitcnt vmcnt(4)" ::: "memory");
    __builtin_amdgcn_sched_barrier(0);
    __builtin_amdgcn_s_barrier();
    __builtin_amdgcn_sched_barrier(0);
    __builtin_amdgcn_s_setprio(1);
    acc[4][0] = __builtin_amdgcn_mfma_f32_16x16x32_bf16(a4, b0, acc[4][0], 0, 0, 0);
    acc[4][1] = __builtin_amdgcn_mfma_f32_16x16x32_bf16(a4, b1, acc[4][1], 0, 0, 0);
    acc[4][2] = __builtin_amdgcn_mfma_f32_16x16x32_bf16(a4, b2, acc[4][2], 0, 0, 0);
    acc[4][3] = __builtin_amdgcn_mfma_f32_16x16x32_bf16(a4, b3, acc[4][3], 0, 0, 0);
    acc[5][0] = __builtin_amdgcn_mfma_f32_16x16x32_bf16(a5, b0, acc[5][0], 0, 0, 0);
    acc[5][1] = __builtin_amdgcn_mfma_f32_16x16x32_bf16(a5, b1, acc[5][1], 0, 0, 0);
    acc[5][2] = __builtin_amdgcn_mfma_f32_16x16x32_bf16(a5, b2, acc[5][2], 0, 0, 0);
    acc[5][3] = __builtin_amdgcn_mfma_f32_16x16x32_bf16(a5, b3, acc[5][3], 0, 0, 0);
    acc[6][0] = __builtin_amdgcn_mfma_f32_16x16x32_bf16(a6, b0, acc[6][0], 0, 0, 0);
    acc[6][1] = __builtin_amdgcn_mfma_f32_16x16x32_bf16(a6, b1, acc[6][1], 0, 0, 0);
    acc[6][2] = __builtin_amdgcn_mfma_f32_16x16x32_bf16(a6, b2, acc[6][2], 0, 0, 0);
    acc[6][3] = __builtin_amdgcn_mfma_f32_16x16x32_bf16(a6, b3, acc[6][3], 0, 0, 0);
    acc[7][0] = __builtin_amdgcn_mfma_f32_16x16x32_bf16(a7, b0, acc[7][0], 0, 0, 0);
    acc[7][1] = __builtin_amdgcn_mfma_f32_16x16x32_bf16(a7, b1, acc[7][1], 0, 0, 0);
    acc[7][2] = __builtin_amdgcn_mfma_f32_16x16x32_bf16(a7, b2, acc[7][2], 0, 0, 0);
    acc[7][3] = __builtin_amdgcn_mfma_f32_16x16x32_bf16(a7, b3, acc[7][3], 0, 0, 0);
    __builtin_amdgcn_s_setprio(0);
    __builtin_amdgcn_sched_barrier(0);
    __builtin_amdgcn_s_barrier();
    __builtin_amdgcn_sched_barrier(0);
    tb++; if (tb == 3) tb = 0;
  }

  // epilogue
  #pragma unroll
  for (int nf = 0; nf < 4; nf++) {
    const int col = n0 + wc * 64 + nf * 16 + (l & 15);
    const float bv = bias[col];
    #pragma unroll
    for (int mf = 0; mf < 8; mf++) {
      const int rowb = m0 + wr * 128 + mf * 16 + (l >> 4) * 4;
      #pragma unroll
      for (int r = 0; r < 4; r++) {
        float v = acc[mf][nf][r] + bv;
        if (OUTMODE == 2) {
          const int seg = col >> 11;
          v = (seg == 2) ? tanhf(v) : sigmoidf_(v);
          const size_t idx = (size_t)seg * M * 2048 + (size_t)(rowb + r) * 2048 + (col & 2047);
          ((unsigned short*)Cout)[idx] = f2b(v);
        } else {
          ((unsigned short*)Cout)[(size_t)(rowb + r) * N + col] = f2b(v);
        }
      }
    }
  }
}

// ---------------------------------------------------------------------------
// 128x128 GEMM (old structure) — kept for the Wo GEMM (N=1024 grid shape).
// OUTMODE 1: fp32 + residual.
// ---------------------------------------------------------------------------
template <int ACT, int OUTMODE>
__global__ __launch_bounds__(256) void gemm_bt(
    const unsigned short* __restrict__ A, const unsigned short* __restrict__ Bt,
    const float* __restrict__ bias, void* __restrict__ Cout,
    const float* __restrict__ resid, int M, int N, int K) {
  __shared__ unsigned short Alds[128 * 32];
  __shared__ unsigned short Blds[128 * 32];
  const int tid = threadIdx.x;
  const int m0 = blockIdx.y * 128, n0 = blockIdx.x * 128;
  const int l = tid & 63, w = tid >> 6;
  const int wr = w >> 1, wc = w & 1;

  f32x4 acc[4][4];
  #pragma unroll
  for (int i = 0; i < 4; i++)
    #pragma unroll
    for (int j = 0; j < 4; j++) acc[i][j] = (f32x4){0.f, 0.f, 0.f, 0.f};

  const int c0 = tid, c1 = tid + 256;
  const unsigned short* Ag0 = A + (size_t)(m0 + (c0 >> 2)) * K + (c0 & 3) * 8;
  const unsigned short* Ag1 = A + (size_t)(m0 + (c1 >> 2)) * K + (c1 & 3) * 8;
  const unsigned short* Bg0 = Bt + (size_t)(n0 + (c0 >> 2)) * K + (c0 & 3) * 8;
  const unsigned short* Bg1 = Bt + (size_t)(n0 + (c1 >> 2)) * K + (c1 & 3) * 8;
  const int frag_off = (l & 15) * 32 + (l >> 4) * 8;

  for (int k0 = 0; k0 < K; k0 += 32) {
    __builtin_amdgcn_global_load_lds(GPTR(Ag0 + k0), LPTR(&Alds[c0 * 8]), 16, 0, 0);
    __builtin_amdgcn_global_load_lds(GPTR(Ag1 + k0), LPTR(&Alds[c1 * 8]), 16, 0, 0);
    __builtin_amdgcn_global_load_lds(GPTR(Bg0 + k0), LPTR(&Blds[c0 * 8]), 16, 0, 0);
    __builtin_amdgcn_global_load_lds(GPTR(Bg1 + k0), LPTR(&Blds[c1 * 8]), 16, 0, 0);
    __syncthreads();
    bf16x8 af[4], bfv[4];
    #pragma unroll
    for (int m = 0; m < 4; m++)
      af[m] = *(const bf16x8*)(&Alds[(wr * 64 + m * 16) * 32 + frag_off]);
    #pragma unroll
    for (int n = 0; n < 4; n++)
      bfv[n] = *(const bf16x8*)(&Blds[(wc * 64 + n * 16) * 32 + frag_off]);
    #pragma unroll
    for (int m = 0; m < 4; m++)
      #pragma unroll
      for (int n = 0; n < 4; n++)
        acc[m][n] = __builtin_amdgcn_mfma_f32_16x16x32_bf16(af[m], bfv[n], acc[m][n], 0, 0, 0);
    __syncthreads();
  }

  #pragma unroll
  for (int n = 0; n < 4; n++) {
    const int col = n0 + wc * 64 + n * 16 + (l & 15);
    const float bv = bias[col];
    #pragma unroll
    for (int m = 0; m < 4; m++) {
      const int rowb = m0 + wr * 64 + m * 16 + (l >> 4) * 4;
      #pragma unroll
      for (int r = 0; r < 4; r++) {
        float v = acc[m][n][r] + bv;
        if (ACT == 1) v = sigmoidf_(v);
        else if (ACT == 2) v = tanhf(v);
        const size_t idx = (size_t)(rowb + r) * N + col;
        if (OUTMODE == 0) ((unsigned short*)Cout)[idx] = f2b(v);
        else ((float*)Cout)[idx] = v + resid[idx];
      }
    }
  }
}

// ---------------------------------------------------------------------------
// Causal depthwise conv (K=3) + SiLU + gate.  proj bf16 [B*S][2*INNER].
// ---------------------------------------------------------------------------
__global__ __launch_bounds__(256) void conv_gate_kernel(
    const unsigned short* __restrict__ proj, const float* __restrict__ conv_w,
    const float* __restrict__ conv_b, unsigned short* __restrict__ u) {
  const size_t idx = ((size_t)blockIdx.x * 256 + threadIdx.x) * 8;
  const int d = (int)(idx & (INNER - 1));
  const size_t bt = idx >> 11;
  const int t = (int)(bt & (SS - 1));
  const size_t rowbase = bt * (2 * INNER);
  const ushort8 zero = {0, 0, 0, 0, 0, 0, 0, 0};
  ushort8 p0 = *(const ushort8*)(proj + rowbase + d);
  ushort8 p1 = zero, p2 = zero;
  if (t >= 1) p1 = *(const ushort8*)(proj + rowbase - 2 * INNER + d);
  if (t >= 2) p2 = *(const ushort8*)(proj + rowbase - 4 * INNER + d);
  ushort8 g = *(const ushort8*)(proj + rowbase + INNER + d);
  ushort8 res;
  #pragma unroll
  for (int j = 0; j < 8; j++) {
    const int dj = d + j;
    float sv = conv_b[dj] + conv_w[dj * 3] * b2f(p2[j]) +
               conv_w[dj * 3 + 1] * b2f(p1[j]) + conv_w[dj * 3 + 2] * b2f(p0[j]);
    float uu = sv * sigmoidf_(sv) * sigmoidf_(b2f(g[j]));
    res[j] = f2b(uu);
  }
  *(ushort8*)(u + idx) = res;
}

// ---------------------------------------------------------------------------
// Chunked parallel scan, 3 phases.
// ---------------------------------------------------------------------------
__global__ __launch_bounds__(256) void scan_phase1(
    const unsigned short* __restrict__ a, const unsigned short* __restrict__ b,
    const unsigned short* __restrict__ u,
    float* __restrict__ P, float* __restrict__ S) {
  const int g = blockIdx.x * 256 + threadIdx.x;   // 65536 threads
  const int ch = (g & (INNER / 4 - 1)) * 4;
  const int chunk = (g >> 9) & (NCHK - 1);
  const int bb = g >> 14;
  size_t base = ((size_t)bb * SS + (size_t)chunk * CHUNK) * INNER + ch;
  float st0 = 0.f, st1 = 0.f, st2 = 0.f, st3 = 0.f;
  float p0 = 1.f, p1 = 1.f, p2 = 1.f, p3 = 1.f;
  for (int t = 0; t < CHUNK; t++) {
    const ushort4v av = *(const ushort4v*)(a + base);
    const ushort4v bv = *(const ushort4v*)(b + base);
    const ushort4v uv = *(const ushort4v*)(u + base);
    const float a0 = b2f(av[0]), a1 = b2f(av[1]), a2 = b2f(av[2]), a3 = b2f(av[3]);
    st0 = fmaf(a0, st0, b2f(bv[0]) * b2f(uv[0])); p0 *= a0;
    st1 = fmaf(a1, st1, b2f(bv[1]) * b2f(uv[1])); p1 *= a1;
    st2 = fmaf(a2, st2, b2f(bv[2]) * b2f(uv[2])); p2 *= a2;
    st3 = fmaf(a3, st3, b2f(bv[3]) * b2f(uv[3])); p3 *= a3;
    base += INNER;
  }
  const size_t o = ((size_t)bb * NCHK + chunk) * INNER + ch;
  *(float4*)(P + o) = (float4){p0, p1, p2, p3};
  *(float4*)(S + o) = (float4){st0, st1, st2, st3};
}

__global__ __launch_bounds__(256) void scan_phase2(
    const float* __restrict__ P, const float* __restrict__ S,
    float* __restrict__ Carry) {
  const int g = blockIdx.x * 256 + threadIdx.x;   // 8192 threads
  const int ch = g & (INNER - 1);
  const int bb = g >> 11;
  float carry = 0.f;
  for (int k = 0; k < NCHK; k++) {
    const size_t o = ((size_t)bb * NCHK + k) * INNER + ch;
    Carry[o] = carry;
    carry = fmaf(P[o], carry, S[o]);
  }
}

__global__ __launch_bounds__(256) void scan_phase3(
    const unsigned short* __restrict__ a, const unsigned short* __restrict__ b,
    const unsigned short* __restrict__ c, unsigned short* __restrict__ u,
    const float* __restrict__ Carry) {
  const int g = blockIdx.x * 256 + threadIdx.x;   // 65536 threads
  const int ch = (g & (INNER / 4 - 1)) * 4;
  const int chunk = (g >> 9) & (NCHK - 1);
  const int bb = g >> 14;
  size_t base = ((size_t)bb * SS + (size_t)chunk * CHUNK) * INNER + ch;
  const size_t o = ((size_t)bb * NCHK + chunk) * INNER + ch;
  const float4 cv = *(const float4*)(Carry + o);
  float st0 = cv.x, st1 = cv.y, st2 = cv.z, st3 = cv.w;
  for (int t = 0; t < CHUNK; t++) {
    const ushort4v av = *(const ushort4v*)(a + base);
    const ushort4v bv = *(const ushort4v*)(b + base);
    const ushort4v ccv = *(const ushort4v*)(c + base);
    const ushort4v uv = *(const ushort4v*)(u + base);
    const float u0 = b2f(uv[0]), u1 = b2f(uv[1]), u2 = b2f(uv[2]), u3 = b2f(uv[3]);
    st0 = fmaf(b2f(av[0]), st0, b2f(bv[0]) * u0);
    st1 = fmaf(b2f(av[1]), st1, b2f(bv[1]) * u1);
    st2 = fmaf(b2f(av[2]), st2, b2f(bv[2]) * u2);
    st3 = fmaf(b2f(av[3]), st3, b2f(bv[3]) * u3);
    ushort4v yv;
    yv[0] = f2b(fmaf(b2f(ccv[0]), st0, u0));
    yv[1] = f2b(fmaf(b2f(ccv[1]), st1, u1));
    yv[2] = f2b(fmaf(b2f(ccv[2]), st2, u2));
    yv[3] = f2b(fmaf(b2f(ccv[3]), st3, u3));
    *(ushort4v*)(u + base) = yv;
    base += INNER;
  }
}

// ---------------------------------------------------------------------------
extern "C" void kernel_launch(void* const* d_in, const int* in_sizes, int n_in,
                              void* d_out, int out_size, void* d_ws, size_t ws_size,
                              hipStream_t stream) {
  const float* x      = (const float*)d_in[0];
  const float* W_in   = (const float*)d_in[1];
  const float* b_in   = (const float*)d_in[2];
  const float* conv_w = (const float*)d_in[3];
  const float* conv_b = (const float*)d_in[4];
  const float* Wa     = (const float*)d_in[5];
  const float* ba     = (const float*)d_in[6];
  const float* Wb     = (const float*)d_in[7];
  const float* b_b    = (const float*)d_in[8];
  const float* Wc     = (const float*)d_in[9];
  const float* bc     = (const float*)d_in[10];
  const float* Wo     = (const float*)d_in[11];
  const float* bo     = (const float*)d_in[12];
  const float* gamma  = (const float*)d_in[13];
  const float* beta   = (const float*)d_in[14];
  float* out = (float*)d_out;

  const size_t M = (size_t)BB * SS;  // 8192
  char* ws = (char*)d_ws;
  size_t off = 0;
  auto alloc = [&](size_t bytes) {
    char* p = ws + off;
    off += (bytes + 255) & ~(size_t)255;
    return p;
  };
  unsigned short* WinT  = (unsigned short*)alloc((size_t)4096 * 1024 * 2);  // 8 MB
  unsigned short* WabcT = (unsigned short*)alloc((size_t)6144 * 2048 * 2);  // 24 MB
  unsigned short* WoT   = (unsigned short*)alloc((size_t)1024 * 2048 * 2);  // 4 MB
  float*          biasABC = (float*)alloc(6144 * 4);
  unsigned short* xnB   = (unsigned short*)alloc(M * DM * 2);               // 16 MB
  unsigned short* uB    = (unsigned short*)alloc(M * INNER * 2);            // 32 MB
  unsigned short* abc   = (unsigned short*)alloc(3 * M * INNER * 2);        // 96 MB
  unsigned short* proj = abc;
  unsigned short* aB = abc;
  unsigned short* bB = abc + M * INNER;
  unsigned short* cB = abc + 2 * M * INNER;
  float* Pbuf  = (float*)xnB;          // xnB dead after proj GEMM
  float* Sbuf  = Pbuf + (size_t)BB * NCHK * INNER;
  float* Carry = Sbuf + (size_t)BB * NCHK * INNER;

  hipMemcpyAsync(biasABC,        ba,  2048 * 4, hipMemcpyDeviceToDevice, stream);
  hipMemcpyAsync(biasABC + 2048, b_b, 2048 * 4, hipMemcpyDeviceToDevice, stream);
  hipMemcpyAsync(biasABC + 4096, bc,  2048 * 4, hipMemcpyDeviceToDevice, stream);

  const dim3 tb(32, 8);
  transpose_cast_kernel<<<dim3(128, 32), tb, 0, stream>>>(W_in, WinT, 1024, 4096);
  transpose_cast_kernel<<<dim3(64, 64), tb, 0, stream>>>(Wa, WabcT, 2048, 2048);
  transpose_cast_kernel<<<dim3(64, 64), tb, 0, stream>>>(Wb, WabcT + 2048 * 2048, 2048, 2048);
  transpose_cast_kernel<<<dim3(64, 64), tb, 0, stream>>>(Wc, WabcT + 2 * 2048 * 2048, 2048, 2048);
  transpose_cast_kernel<<<dim3(32, 64), tb, 0, stream>>>(Wo, WoT, 2048, 1024);

  layernorm_kernel<<<M, 256, 0, stream>>>(x, gamma, beta, xnB);

  // proj = xn @ W_in + b_in            [8192 x 4096]
  gemm256<0><<<dim3(4096 / 256, M / 256), 512, 0, stream>>>(
      xnB, WinT, b_in, proj, M, 4096, 1024);

  // u = silu(conv(projected)) * sigmoid(gate)
  conv_gate_kernel<<<(M * INNER) / (256 * 8), 256, 0, stream>>>(proj, conv_w, conv_b, uB);

  // a,b,c fused: [8192 x 6144] over concatenated [Wa;Wb;Wc]^T
  gemm256<2><<<dim3(6144 / 256, M / 256), 512, 0, stream>>>(
      uB, WabcT, biasABC, abc, M, 6144, 2048);

  // chunked scan (y overwrites u)
  scan_phase1<<<256, 256, 0, stream>>>(aB, bB, uB, Pbuf, Sbuf);
  scan_phase2<<<32, 256, 0, stream>>>(Pbuf, Sbuf, Carry);
  scan_phase3<<<256, 256, 0, stream>>>(aB, bB, cB, uB, Carry);

  // out = x + y @ Wo + bo              [8192 x 1024] fp32
  gemm_bt<0, 1><<<dim3(8, 64), 256, 0, stream>>>(
      uB, WoT, bo, out, x, M, 1024, 2048);
}